// Round 5
// baseline (201.398 us; speedup 1.0000x reference)
//
#include <hip/hip_runtime.h>

#define D 64
#define KCODES 512
#define BLOCK 256
#define RPB 128          // rows per block (4 waves x 32 rows)
#define CHUNK 64         // codes staged in LDS per iteration
#define NCHUNK (KCODES / CHUNK)
#define CBS 72           // LDS stride (shorts) per code row

typedef short  short8  __attribute__((ext_vector_type(8)));
typedef unsigned short ushort8 __attribute__((ext_vector_type(8)));
typedef float  f32x4   __attribute__((ext_vector_type(4)));

// fp32 -> bf16 RNE (hi) + bf16 of remainder (lo). Inputs are moderate normals.
__device__ __forceinline__ void bf16_split(float f, unsigned short& h, unsigned short& l) {
    union { float f; unsigned u; } a; a.f = f;
    unsigned r = a.u + 0x7FFFu + ((a.u >> 16) & 1u);
    h = (unsigned short)(r >> 16);
    union { unsigned u; float f; } b; b.u = (unsigned)h << 16;
    float rem = f - b.f;
    union { float f; unsigned u; } c; c.f = rem;
    unsigned r2 = c.u + 0x7FFFu + ((c.u >> 16) & 1u);
    l = (unsigned short)(r2 >> 16);
}

// prep: cc[k]=||c_k||^2 (round-1 fma order) and bf16 hi/lo of (-2*c) into ws.
__global__ __launch_bounds__(256) void vq_prep(const float* __restrict__ cb,
                                               unsigned short* __restrict__ wh,
                                               unsigned short* __restrict__ wl,
                                               float* __restrict__ cc) {
    const int k = blockIdx.x * 256 + threadIdx.x;
    if (k >= KCODES) return;
    const float4* cv = (const float4*)(cb + k * D);
    float s = 0.f;
    #pragma unroll
    for (int db = 0; db < 16; ++db) {
        float4 q = cv[db];
        s = fmaf(q.x, q.x, s); s = fmaf(q.y, q.y, s);
        s = fmaf(q.z, q.z, s); s = fmaf(q.w, q.w, s);
        float v[4] = {q.x, q.y, q.z, q.w};
        #pragma unroll
        for (int j = 0; j < 4; ++j) {
            unsigned short h, l;
            bf16_split(-2.f * v[j], h, l);
            wh[k * D + db * 4 + j] = h;
            wl[k * D + db * 4 + j] = l;
        }
    }
    cc[k] = s;
}

__global__ __launch_bounds__(BLOCK, 4) void vq_mfma(const float* __restrict__ x,
                                                    const float* __restrict__ cb,
                                                    const unsigned short* __restrict__ wh,
                                                    const unsigned short* __restrict__ wl,
                                                    const float* __restrict__ ccg,
                                                    float* __restrict__ out) {
    __shared__ unsigned short s_cbh[CHUNK * CBS];   // 9 KB
    __shared__ unsigned short s_cbl[CHUNK * CBS];   // 9 KB
    __shared__ float s_cc[KCODES];                  // 2 KB
    __shared__ float s_xx[RPB];
    __shared__ int   s_bi[RPB];
    __shared__ int   s_flag[RPB];
    __shared__ int   s_nflag;

    const int t    = threadIdx.x;
    const int w    = t >> 6;
    const int lane = t & 63;
    const int quad = lane >> 4;
    const int col  = lane & 15;
    const float4* xv4  = (const float4*)x;
    const float4* cbv4 = (const float4*)cb;

    if (t == 0) s_nflag = 0;

    // A-fragments: wave w owns rows w*32..w*32+31 (2 row-tiles).
    // A layout (validated round 4): m = lane&15, d = kt*32 + quad*8 + j.
    short8 xh[2][2], xl[2][2];
    const size_t growb = (size_t)blockIdx.x * RPB + w * 32;
    #pragma unroll
    for (int rt = 0; rt < 2; ++rt) {
        const size_t row = growb + rt * 16 + col;
        #pragma unroll
        for (int kt = 0; kt < 2; ++kt) {
            float4 p0 = xv4[row * 16 + kt * 8 + quad * 2];
            float4 p1 = xv4[row * 16 + kt * 8 + quad * 2 + 1];
            float v[8] = {p0.x, p0.y, p0.z, p0.w, p1.x, p1.y, p1.z, p1.w};
            short8 hh, ll;
            #pragma unroll
            for (int j = 0; j < 8; ++j) {
                unsigned short h, l;
                bf16_split(v[j], h, l);
                hh[j] = (short)h; ll[j] = (short)l;
            }
            xh[rt][kt] = hh; xl[rt][kt] = ll;
        }
    }

    // waves 0,1: xx per row (round-1 order); waves 2,3: stage cc into LDS.
    if (t < RPB) {
        const size_t gr = (size_t)blockIdx.x * RPB + t;
        float s = 0.f;
        #pragma unroll
        for (int db = 0; db < 16; ++db) {
            float4 q = xv4[gr * 16 + db];
            s = fmaf(q.x, q.x, s); s = fmaf(q.y, q.y, s);
            s = fmaf(q.z, q.z, s); s = fmaf(q.w, q.w, s);
        }
        s_xx[t] = s;
    } else {
        const int k4 = (t - RPB) * 4;
        *(float4*)&s_cc[k4] = *(const float4*)&ccg[k4];
    }
    __syncthreads();

    // per-lane xx for C/D rows: row = quad*4 + r (validated round 4)
    float xxr[8];
    #pragma unroll
    for (int rt = 0; rt < 2; ++rt)
        #pragma unroll
        for (int r = 0; r < 4; ++r)
            xxr[rt * 4 + r] = s_xx[w * 32 + rt * 16 + quad * 4 + r];

    float best[8], second[8]; int bis[8];
    #pragma unroll
    for (int i = 0; i < 8; ++i) { best[i] = __builtin_inff(); second[i] = __builtin_inff(); bis[i] = 0; }

    for (int c = 0; c < NCHUNK; ++c) {
        if (c) __syncthreads();           // previous chunk consumed
        // stage pre-split chunk: 512 ushort8 units per array, 2 per thread
        const ushort8* gh = (const ushort8*)(wh + c * CHUNK * D);
        const ushort8* gl = (const ushort8*)(wl + c * CHUNK * D);
        #pragma unroll
        for (int i = 0; i < 2; ++i) {
            const int u = i * 256 + t;
            const int lc = u >> 3, seg = u & 7;
            *(ushort8*)&s_cbh[lc * CBS + seg * 8] = gh[u];
            *(ushort8*)&s_cbl[lc * CBS + seg * 8] = gl[u];
        }
        __syncthreads();

        #pragma unroll 2
        for (int ct = 0; ct < CHUNK / 16; ++ct) {
            const int lc = ct * 16 + col;           // B layout: n = lane&15
            short8 ch0 = *(const short8*)&s_cbh[lc * CBS + quad * 8];
            short8 ch1 = *(const short8*)&s_cbh[lc * CBS + 32 + quad * 8];
            short8 cl0 = *(const short8*)&s_cbl[lc * CBS + quad * 8];
            short8 cl1 = *(const short8*)&s_cbl[lc * CBS + 32 + quad * 8];
            const int   kglob = c * CHUNK + ct * 16 + col;
            const float cck   = s_cc[kglob];

            #pragma unroll
            for (int rt = 0; rt < 2; ++rt) {
                f32x4 acc;
                #pragma unroll
                for (int r = 0; r < 4; ++r) acc[r] = xxr[rt * 4 + r] + cck;
                // dist = (xx + cc) + sum((-2c)*x); 3-product split (ll dropped,
                // ~1e-5 error << 1e-3 hedge threshold)
                acc = __builtin_amdgcn_mfma_f32_16x16x32_bf16(xh[rt][0], ch0, acc, 0, 0, 0);
                acc = __builtin_amdgcn_mfma_f32_16x16x32_bf16(xl[rt][0], ch0, acc, 0, 0, 0);
                acc = __builtin_amdgcn_mfma_f32_16x16x32_bf16(xh[rt][0], cl0, acc, 0, 0, 0);
                acc = __builtin_amdgcn_mfma_f32_16x16x32_bf16(xh[rt][1], ch1, acc, 0, 0, 0);
                acc = __builtin_amdgcn_mfma_f32_16x16x32_bf16(xl[rt][1], ch1, acc, 0, 0, 0);
                acc = __builtin_amdgcn_mfma_f32_16x16x32_bf16(xh[rt][1], cl1, acc, 0, 0, 0);
                #pragma unroll
                for (int r = 0; r < 4; ++r) {
                    const int idx = rt * 4 + r;
                    const float dist = acc[r];
                    second[idx] = fminf(second[idx], fmaxf(best[idx], dist));
                    if (dist < best[idx]) { best[idx] = dist; bis[idx] = kglob; }
                }
            }
        }
    }

    // argmin across the 16 code-lanes per (rt,r) row (validated round 4)
    #pragma unroll
    for (int rt = 0; rt < 2; ++rt) {
        #pragma unroll
        for (int r = 0; r < 4; ++r) {
            const int idx = rt * 4 + r;
            float b = best[idx], s2 = second[idx]; int bi = bis[idx];
            #pragma unroll
            for (int off = 1; off < 16; off <<= 1) {
                float ob  = __shfl_xor(b, off);
                int   obi = __shfl_xor(bi, off);
                float os  = __shfl_xor(s2, off);
                s2 = fminf(fminf(s2, os), fmaxf(b, ob));
                if (ob < b || (ob == b && obi < bi)) { b = ob; bi = obi; }
            }
            if (col == 0) {
                const int row = w * 32 + rt * 16 + quad * 4 + r;
                s_bi[row] = bi;
                if (s2 - b < 1e-3f) {
                    int p = atomicAdd(&s_nflag, 1);
                    s_flag[p] = row;
                }
            }
        }
    }
    __syncthreads();

    // exact fp32 re-argmin for near-tie rows (validated round 4; rare path)
    const int nf = s_nflag;
    for (int i = w; i < nf; i += 4) {
        const int row = s_flag[i];
        const size_t gr = (size_t)blockIdx.x * RPB + row;
        float4 xr4[16];
        #pragma unroll
        for (int db = 0; db < 16; ++db) xr4[db] = xv4[gr * 16 + db];
        const float xxv = s_xx[row];
        float b = __builtin_inff(); int bi = 0;
        for (int kk = 0; kk < 8; ++kk) {
            const int k = lane * 8 + kk;
            float dot0 = 0.f, dot1 = 0.f;
            #pragma unroll
            for (int db = 0; db < 16; ++db) {
                float4 cq = cbv4[k * 16 + db];
                dot0 = fmaf(xr4[db].x, cq.x, dot0);
                dot1 = fmaf(xr4[db].y, cq.y, dot1);
                dot0 = fmaf(xr4[db].z, cq.z, dot0);
                dot1 = fmaf(xr4[db].w, cq.w, dot1);
            }
            const float dist = (xxv - 2.f * (dot0 + dot1)) + s_cc[k];
            if (dist < b) { b = dist; bi = k; }
        }
        #pragma unroll
        for (int off = 1; off < 64; off <<= 1) {
            float ob  = __shfl_xor(b, off);
            int   obi = __shfl_xor(bi, off);
            if (ob < b || (ob == b && obi < bi)) { b = ob; bi = obi; }
        }
        if (lane == 0) s_bi[row] = bi;
    }
    __syncthreads();

    // coalesced gather+store (validated round 2/4)
    float4* outv = (float4*)out + (size_t)blockIdx.x * (RPB * 16);
    #pragma unroll
    for (int j = 0; j < RPB * 16 / BLOCK; ++j) {
        const int f4 = j * BLOCK + t;
        const int r  = f4 >> 4;
        const int q  = f4 & 15;
        outv[f4] = cbv4[s_bi[r] * 16 + q];
    }
}

extern "C" void kernel_launch(void* const* d_in, const int* in_sizes, int n_in,
                              void* d_out, int out_size, void* d_ws, size_t ws_size,
                              hipStream_t stream) {
    const float* x  = (const float*)d_in[0];   // 131072 x 64
    const float* cb = (const float*)d_in[1];   // 512 x 64
    float* out = (float*)d_out;

    unsigned short* wh = (unsigned short*)d_ws;                      // 64 KB
    unsigned short* wl = (unsigned short*)((char*)d_ws + 65536);     // 64 KB
    float*          cc = (float*)((char*)d_ws + 131072);             // 2 KB

    vq_prep<<<2, 256, 0, stream>>>(cb, wh, wl, cc);

    const int N = in_sizes[0] / D;             // 131072
    vq_mfma<<<N / RPB, BLOCK, 0, stream>>>(x, cb, wh, wl, cc, out);
}